// Round 1
// baseline (226.152 us; speedup 1.0000x reference)
//
#include <hip/hip_runtime.h>
#include <stdint.h>

#define B_  32
#define M_  1024
#define DF  128   // feature dim
#define ED  64    // embedding dim

typedef __attribute__((ext_vector_type(8))) short short8;   // 8 bf16 (4 VGPRs)
typedef __attribute__((ext_vector_type(4))) float floatx4;  // MFMA C/D

__device__ inline unsigned short f2bf(float f) {
    union { float f; unsigned u; } v; v.f = f;
    unsigned r = v.u + 0x7fffu + ((v.u >> 16) & 1u);
    return (unsigned short)(r >> 16);
}

// ---------------------------------------------------------------- cast kernel
__global__ __launch_bounds__(256) void cast_kernel(
    const float* __restrict__ E, const float* __restrict__ W1,
    const float* __restrict__ W2, unsigned short* __restrict__ Ebf,
    unsigned short* __restrict__ W1bf, unsigned short* __restrict__ W2bf) {
    const int NE = B_ * M_ * ED;          // 2,097,152
    const int NW = DF * DF;               // 16,384
    int idx = (blockIdx.x * 256 + threadIdx.x) * 4;
    const float* src; unsigned short* dst; int off;
    if (idx < NE)            { src = E;  dst = Ebf;  off = idx; }
    else if (idx < NE + NW)  { src = W1; dst = W1bf; off = idx - NE; }
    else                     { src = W2; dst = W2bf; off = idx - NE - NW; }
    float4 v = *(const float4*)(src + off);
    ushort4 o;
    o.x = f2bf(v.x); o.y = f2bf(v.y); o.z = f2bf(v.z); o.w = f2bf(v.w);
    *(ushort4*)(dst + off) = o;
}

// ---------------------------------------------------------------- degree
// d_m = 1 + sum_n relu(e_m . e_n) ; dinv = rsqrt(d)
__global__ __launch_bounds__(256) void degree_kernel(
    const unsigned short* __restrict__ Ebf, float* __restrict__ dinv) {
    int mt = blockIdx.x, b = blockIdx.y;
    int t = threadIdx.x;
    int w = t >> 6, lane = t & 63, quad = lane >> 4, lc = lane & 15;
    __shared__ unsigned short sEn[128][72];   // +8 pad: 2-way (free) bank aliasing
    const unsigned short* Eb = Ebf + (size_t)b * M_ * ED;

    short8 afr[2][2];                         // wave rows: w*32 + i*16 + lc
    for (int i = 0; i < 2; ++i) {
        int row = mt * 128 + w * 32 + i * 16 + lc;
        for (int ks = 0; ks < 2; ++ks)
            afr[i][ks] = *(const short8*)(Eb + (size_t)row * ED + ks * 32 + quad * 8);
    }
    floatx4 rsum[2];
    rsum[0] = (floatx4){0.f,0.f,0.f,0.f};
    rsum[1] = (floatx4){0.f,0.f,0.f,0.f};

    for (int nc = 0; nc < 8; ++nc) {
        __syncthreads();
        for (int it = 0; it < 4; ++it) {
            int c = t + 256 * it;             // 1024 chunks = 128 rows x 8
            int row = c >> 3, off = (c & 7) * 8;
            *(short8*)(&sEn[row][off]) =
                *(const short8*)(Eb + (size_t)(nc * 128 + row) * ED + off);
        }
        __syncthreads();
        for (int nt = 0; nt < 8; ++nt) {
            short8 b0 = *(const short8*)(&sEn[nt * 16 + lc][quad * 8]);
            short8 b1 = *(const short8*)(&sEn[nt * 16 + lc][32 + quad * 8]);
            for (int i = 0; i < 2; ++i) {
                floatx4 s = (floatx4){0.f,0.f,0.f,0.f};
                s = __builtin_amdgcn_mfma_f32_16x16x32_bf16(afr[i][0], b0, s, 0, 0, 0);
                s = __builtin_amdgcn_mfma_f32_16x16x32_bf16(afr[i][1], b1, s, 0, 0, 0);
                for (int r = 0; r < 4; ++r) rsum[i][r] += fmaxf(s[r], 0.f);
            }
        }
    }
    for (int i = 0; i < 2; ++i)
        for (int r = 0; r < 4; ++r) {
            float v = rsum[i][r];
            v += __shfl_xor(v, 1, 16);
            v += __shfl_xor(v, 2, 16);
            v += __shfl_xor(v, 4, 16);
            v += __shfl_xor(v, 8, 16);
            if (lc == 0) {
                int row = mt * 128 + w * 32 + i * 16 + quad * 4 + r;
                dinv[b * M_ + row] = rsqrtf(1.0f + v);
            }
        }
}

// ---------------------------------------------------------------- Xt = (dinv_n * X)^T  (bf16)
__global__ __launch_bounds__(256) void tscale_kernel(
    const float* __restrict__ X, const float* __restrict__ dinv,
    unsigned short* __restrict__ Xt) {
    int mt = blockIdx.x, b = blockIdx.y;      // mt = n-tile
    int t = threadIdx.x;
    __shared__ unsigned short sT[128][136];
    int nloc = t >> 5;                        // 0..7
    int d4 = (t & 31) * 4;
    for (int pass = 0; pass < 16; ++pass) {
        int n = pass * 8 + nloc;
        int grow = b * M_ + mt * 128 + n;
        float sc = dinv[grow];
        float4 v = *(const float4*)(X + (size_t)grow * DF + d4);
        sT[d4 + 0][n] = f2bf(v.x * sc);
        sT[d4 + 1][n] = f2bf(v.y * sc);
        sT[d4 + 2][n] = f2bf(v.z * sc);
        sT[d4 + 3][n] = f2bf(v.w * sc);
    }
    __syncthreads();
    for (int it = 0; it < 8; ++it) {
        int c = t + 256 * it;                 // 2048 = 128 rows x 16
        int d = c >> 4, off = (c & 15) * 8;
        *(short8*)(Xt + (size_t)(b * DF + d) * M_ + mt * 128 + off) =
            *(const short8*)(&sT[d][off]);
    }
}

// ---------------------------------------------------------------- fused GCN layer
// MODE 1: OutT[b][o][m] = bf16(dinv_m * relu((dinv*Z) @ W^T))   (layer-2 input, k-contig)
// MODE 2: OutF[m][o]    = fp32(relu((dinv*Z) @ W^T))            (final output)
template <int MODE>
__global__ __launch_bounds__(256) void gcn_kernel(
    const unsigned short* __restrict__ Ebf,
    const unsigned short* __restrict__ Pt,    // [b][128 d][1024 n] bf16, dinv_n-scaled
    const unsigned short* __restrict__ Wbf,   // [128 o][128 i] bf16 row-major
    const float* __restrict__ dinv,
    unsigned short* __restrict__ OutT,
    float* __restrict__ OutF) {
    int mt = blockIdx.x, b = blockIdx.y;
    int t = threadIdx.x;
    int w = t >> 6, lane = t & 63, quad = lane >> 4, lc = lane & 15;
    int wr = w & 1, wc = w >> 1;              // wave quadrant of the 128x128 tile

    __shared__ unsigned short sEn[128][72];
    __shared__ unsigned short sS[128][136];   // S tile, then Y, then transpose buf
    __shared__ unsigned short sPW[128][136];  // P chunk in main loop, W in epilogue

    const unsigned short* Eb = Ebf + (size_t)b * M_ * ED;

    // hoisted stage-1 A frags (Em rows are block-static): rows wr*64 + i*16 + lc
    short8 ae[4][2];
    for (int i = 0; i < 4; ++i) {
        int row = mt * 128 + wr * 64 + i * 16 + lc;
        for (int ks = 0; ks < 2; ++ks)
            ae[i][ks] = *(const short8*)(Eb + (size_t)row * ED + ks * 32 + quad * 8);
    }
    floatx4 accZ[4][4];
    for (int i = 0; i < 4; ++i)
        for (int j = 0; j < 4; ++j) accZ[i][j] = (floatx4){0.f,0.f,0.f,0.f};

    for (int nc = 0; nc < 8; ++nc) {
        __syncthreads();
        for (int it = 0; it < 4; ++it) {      // E chunk: 128 x 64
            int c = t + 256 * it;
            int row = c >> 3, off = (c & 7) * 8;
            *(short8*)(&sEn[row][off]) =
                *(const short8*)(Eb + (size_t)(nc * 128 + row) * ED + off);
        }
        for (int it = 0; it < 8; ++it) {      // P chunk: 128 d x 128 n
            int c = t + 256 * it;
            int drow = c >> 4, off = (c & 15) * 8;
            *(short8*)(&sPW[drow][off]) =
                *(const short8*)(Pt + (size_t)(b * DF + drow) * M_ + nc * 128 + off);
        }
        __syncthreads();
        // stage 1: S = relu(Em En^T) (+I on the diagonal chunk), wave quadrant
        for (int jt = 0; jt < 4; ++jt) {
            int ncol = wc * 64 + jt * 16;
            short8 b0 = *(const short8*)(&sEn[ncol + lc][quad * 8]);
            short8 b1 = *(const short8*)(&sEn[ncol + lc][32 + quad * 8]);
            for (int i = 0; i < 4; ++i) {
                floatx4 s = (floatx4){0.f,0.f,0.f,0.f};
                s = __builtin_amdgcn_mfma_f32_16x16x32_bf16(ae[i][0], b0, s, 0, 0, 0);
                s = __builtin_amdgcn_mfma_f32_16x16x32_bf16(ae[i][1], b1, s, 0, 0, 0);
                int mrow = wr * 64 + i * 16 + quad * 4;
                for (int r = 0; r < 4; ++r) {
                    float v = fmaxf(s[r], 0.f);
                    if (mt == nc && (mrow + r) == (ncol + lc)) v += 1.0f;
                    sS[mrow + r][ncol + lc] = f2bf(v);
                }
            }
        }
        __syncthreads();
        // stage 2: Z += S(wave rows, all 128) @ P(all 128, wave cols)
        for (int ks = 0; ks < 4; ++ks) {
            short8 afr[4];
            for (int i = 0; i < 4; ++i)
                afr[i] = *(const short8*)(&sS[wr * 64 + i * 16 + lc][ks * 32 + quad * 8]);
            for (int j = 0; j < 4; ++j) {
                short8 bfr = *(const short8*)(&sPW[wc * 64 + j * 16 + lc][ks * 32 + quad * 8]);
                for (int i = 0; i < 4; ++i)
                    accZ[i][j] = __builtin_amdgcn_mfma_f32_16x16x32_bf16(afr[i], bfr, accZ[i][j], 0, 0, 0);
            }
        }
    }

    // ---- epilogue: Y = dinv_m * Z ; H = relu(Y @ W^T)
    float dv[4][4];
    for (int i = 0; i < 4; ++i)
        for (int r = 0; r < 4; ++r)
            dv[i][r] = dinv[b * M_ + mt * 128 + wr * 64 + i * 16 + quad * 4 + r];
    __syncthreads();                          // last chunk's sS/sPW reads done
    for (int i = 0; i < 4; ++i)
        for (int j = 0; j < 4; ++j) {
            int mrow = wr * 64 + i * 16 + quad * 4;
            int col = wc * 64 + j * 16 + lc;
            for (int r = 0; r < 4; ++r)
                sS[mrow + r][col] = f2bf(accZ[i][j][r] * dv[i][r]);
        }
    for (int it = 0; it < 8; ++it) {          // W: 128 x 128 row-major
        int c = t + 256 * it;
        int row = c >> 4, off = (c & 15) * 8;
        *(short8*)(&sPW[row][off]) = *(const short8*)(Wbf + row * DF + off);
    }
    __syncthreads();
    floatx4 accH[4][4];
    for (int i = 0; i < 4; ++i)
        for (int j = 0; j < 4; ++j) accH[i][j] = (floatx4){0.f,0.f,0.f,0.f};
    for (int ks = 0; ks < 4; ++ks) {
        short8 afr[4], bfr[4];
        for (int i = 0; i < 4; ++i)
            afr[i] = *(const short8*)(&sS[wr * 64 + i * 16 + lc][ks * 32 + quad * 8]);
        for (int j = 0; j < 4; ++j)
            bfr[j] = *(const short8*)(&sPW[wc * 64 + j * 16 + lc][ks * 32 + quad * 8]);
        for (int i = 0; i < 4; ++i)
            for (int j = 0; j < 4; ++j)
                accH[i][j] = __builtin_amdgcn_mfma_f32_16x16x32_bf16(afr[i], bfr[j], accH[i][j], 0, 0, 0);
    }
    if (MODE == 2) {
        float* Ob = OutF + ((size_t)b * M_ + mt * 128) * DF;
        for (int i = 0; i < 4; ++i)
            for (int j = 0; j < 4; ++j) {
                int mrow = wr * 64 + i * 16 + quad * 4;
                int col = wc * 64 + j * 16 + lc;
                for (int r = 0; r < 4; ++r)
                    Ob[(size_t)(mrow + r) * DF + col] = fmaxf(accH[i][j][r], 0.f);
            }
    } else {
        __syncthreads();                      // done reading sS as Y
        for (int i = 0; i < 4; ++i)
            for (int j = 0; j < 4; ++j) {
                int mrow = wr * 64 + i * 16 + quad * 4;
                int col = wc * 64 + j * 16 + lc;
                for (int r = 0; r < 4; ++r)
                    sS[col][mrow + r] = f2bf(fmaxf(accH[i][j][r], 0.f) * dv[i][r]);
            }
        __syncthreads();
        unsigned short* Ob = OutT + (size_t)b * DF * M_ + mt * 128;
        for (int it = 0; it < 8; ++it) {
            int c = t + 256 * it;
            int orow = c >> 4, off = (c & 15) * 8;
            *(short8*)(Ob + (size_t)orow * M_ + off) = *(const short8*)(&sS[orow][off]);
        }
    }
}

// ---------------------------------------------------------------- launch
extern "C" void kernel_launch(void* const* d_in, const int* in_sizes, int n_in,
                              void* d_out, int out_size, void* d_ws, size_t ws_size,
                              hipStream_t stream) {
    (void)in_sizes; (void)n_in; (void)out_size; (void)ws_size;
    const float* X  = (const float*)d_in[0];   // node_feature_group (B*M, 128)
    const float* E  = (const float*)d_in[1];   // embedding_group    (B*M, 64)
    const float* W1 = (const float*)d_in[2];   // (128, 128)
    const float* W2 = (const float*)d_in[3];   // (128, 128)
    float* out = (float*)d_out;

    char* ws = (char*)d_ws;                    // total ~20.2 MB
    unsigned short* Ebf  = (unsigned short*)(ws);
    unsigned short* W1bf = (unsigned short*)(ws + 4194304);
    unsigned short* W2bf = (unsigned short*)(ws + 4227072);
    float*          dinv = (float*)(ws + 4259840);
    unsigned short* Xt   = (unsigned short*)(ws + 4390912);
    unsigned short* Ht   = (unsigned short*)(ws + 12779520);

    cast_kernel<<<2080, 256, 0, stream>>>(E, W1, W2, Ebf, W1bf, W2bf);
    degree_kernel<<<dim3(8, 32), 256, 0, stream>>>(Ebf, dinv);
    tscale_kernel<<<dim3(8, 32), 256, 0, stream>>>(X, dinv, Xt);
    gcn_kernel<1><<<dim3(8, 32), 256, 0, stream>>>(Ebf, Xt, W1bf, dinv, Ht, nullptr);
    gcn_kernel<2><<<dim3(8, 32), 256, 0, stream>>>(Ebf, Ht, W2bf, dinv, nullptr, out);
}

// Round 3
// 153.840 us; speedup vs baseline: 1.4700x; 1.4700x over previous
//
#include <hip/hip_runtime.h>
#include <stdint.h>

#define B_  32
#define M_  1024
#define DF  128   // feature dim
#define ED  64    // embedding dim

typedef __attribute__((ext_vector_type(8))) short short8;   // 8 bf16 (4 VGPRs)
typedef __attribute__((ext_vector_type(4))) float floatx4;  // MFMA C/D

__device__ inline unsigned short f2bf(float f) {
    union { float f; unsigned u; } v; v.f = f;
    unsigned r = v.u + 0x7fffu + ((v.u >> 16) & 1u);
    return (unsigned short)(r >> 16);
}

__device__ inline void load_lds16(const void* g, void* l) {
    __builtin_amdgcn_global_load_lds(
        (const __attribute__((address_space(1))) unsigned int*)g,
        (__attribute__((address_space(3))) unsigned int*)l, 16, 0, 0);
}

// ---------------------------------------------------------------- cast kernel
__global__ __launch_bounds__(256) void cast_kernel(
    const float* __restrict__ E, const float* __restrict__ W1,
    const float* __restrict__ W2, unsigned short* __restrict__ Ebf,
    unsigned short* __restrict__ W1bf, unsigned short* __restrict__ W2bf) {
    const int NE = B_ * M_ * ED;          // 2,097,152
    const int NW = DF * DF;               // 16,384
    int idx = (blockIdx.x * 256 + threadIdx.x) * 4;
    const float* src; unsigned short* dst; int off;
    if (idx < NE)            { src = E;  dst = Ebf;  off = idx; }
    else if (idx < NE + NW)  { src = W1; dst = W1bf; off = idx - NE; }
    else                     { src = W2; dst = W2bf; off = idx - NE - NW; }
    float4 v = *(const float4*)(src + off);
    ushort4 o;
    o.x = f2bf(v.x); o.y = f2bf(v.y); o.z = f2bf(v.z); o.w = f2bf(v.w);
    *(ushort4*)(dst + off) = o;
}

// ---------------------------------------------------------------- build S + dinv
// S[b][m][n] = bf16(relu(e_m.e_n) + (m==n)) ; dinv[b][m] = rsqrt(rowsum)
// Block = 64-row strip over ALL n -> complete row sums, no atomics.
__global__ __launch_bounds__(256) void build_s_kernel(
    const unsigned short* __restrict__ Ebf, unsigned short* __restrict__ S,
    float* __restrict__ dinv) {
    int mt2 = blockIdx.x, b = blockIdx.y;     // 64-row strip
    int t = threadIdx.x;
    int w = t >> 6, lane = t & 63, quad = lane >> 4, lc = lane & 15;
    __shared__ unsigned short sEn[128][72];
    const unsigned short* Eb = Ebf + (size_t)b * M_ * ED;
    unsigned short* Sg = S + ((size_t)b << 20);
    int base_m = mt2 * 64 + w * 16;

    short8 afr[2];                            // rows base_m + lc
    for (int ks = 0; ks < 2; ++ks)
        afr[ks] = *(const short8*)(Eb + (size_t)(base_m + lc) * ED + ks * 32 + quad * 8);
    floatx4 rsum = (floatx4){0.f, 0.f, 0.f, 0.f};

    for (int nc = 0; nc < 8; ++nc) {
        __syncthreads();
        for (int it = 0; it < 4; ++it) {
            int c = t + 256 * it;             // 1024 = 128 rows x 8
            int row = c >> 3, off = (c & 7) * 8;
            *(short8*)(&sEn[row][off]) =
                *(const short8*)(Eb + (size_t)(nc * 128 + row) * ED + off);
        }
        __syncthreads();
        for (int nt = 0; nt < 8; ++nt) {
            short8 b0 = *(const short8*)(&sEn[nt * 16 + lc][quad * 8]);
            short8 b1 = *(const short8*)(&sEn[nt * 16 + lc][32 + quad * 8]);
            floatx4 s = (floatx4){0.f, 0.f, 0.f, 0.f};
            s = __builtin_amdgcn_mfma_f32_16x16x32_bf16(afr[0], b0, s, 0, 0, 0);
            s = __builtin_amdgcn_mfma_f32_16x16x32_bf16(afr[1], b1, s, 0, 0, 0);
            int n = nc * 128 + nt * 16 + lc;
            for (int r = 0; r < 4; ++r) {
                int m = base_m + quad * 4 + r;
                float v = fmaxf(s[r], 0.f);
                if (m == n) v += 1.0f;
                rsum[r] += v;
                Sg[(size_t)m * M_ + n] = f2bf(v);
            }
        }
    }
    for (int r = 0; r < 4; ++r) {
        float v = rsum[r];
        v += __shfl_xor(v, 1, 16);
        v += __shfl_xor(v, 2, 16);
        v += __shfl_xor(v, 4, 16);
        v += __shfl_xor(v, 8, 16);
        if (lc == 0)
            dinv[b * M_ + base_m + quad * 4 + r] = rsqrtf(v);
    }
}

// ---------------------------------------------------------------- Xt = (dinv_n * X)^T (bf16), 64-row tiles
__global__ __launch_bounds__(256) void tscale_kernel(
    const float* __restrict__ X, const float* __restrict__ dinv,
    unsigned short* __restrict__ Xt) {
    int nt = blockIdx.x, b = blockIdx.y;      // 64 n-rows per block
    int t = threadIdx.x;
    __shared__ unsigned short sT[128][72];
    int nloc = t >> 5;                        // 0..7
    int d4 = (t & 31) * 4;
    for (int pass = 0; pass < 8; ++pass) {
        int n = pass * 8 + nloc;
        int grow = b * M_ + nt * 64 + n;
        float sc = dinv[grow];
        float4 v = *(const float4*)(X + (size_t)grow * DF + d4);
        sT[d4 + 0][n] = f2bf(v.x * sc);
        sT[d4 + 1][n] = f2bf(v.y * sc);
        sT[d4 + 2][n] = f2bf(v.z * sc);
        sT[d4 + 3][n] = f2bf(v.w * sc);
    }
    __syncthreads();
    for (int it = 0; it < 4; ++it) {
        int c = t + 256 * it;                 // 1024 = 128 d-rows x 8
        int d = c >> 3, off = (c & 7) * 8;
        *(short8*)(Xt + (size_t)(b * DF + d) * M_ + nt * 64 + off) =
            *(const short8*)(&sT[d][off]);
    }
}

// ---------------------------------------------------------------- GEMM layer (m97-style)
// Z[m][d] = sum_n S[m][n] * Pt[d][n]; Y = dinv_m*Z; H = relu(Y @ W^T)
// MODE 1: OutT[b][o][m] = bf16(dinv_m * H)  (next layer's Pt)
// MODE 2: OutF[m][o]    = fp32(H)
template <int MODE>
__global__ __launch_bounds__(256) void gemm_kernel(
    const unsigned short* __restrict__ S,
    const unsigned short* __restrict__ Pt,    // [b][128 d][1024 n] bf16
    const unsigned short* __restrict__ Wbf,   // [128 o][128 i] bf16
    const float* __restrict__ dinv,
    unsigned short* __restrict__ OutT,
    float* __restrict__ OutF) {
    int bx = blockIdx.x, b = blockIdx.y;      // 64 m x 128 d tile
    int m0 = bx * 64;
    int t = threadIdx.x;
    int w = t >> 6, lane = t & 63, quad = lane >> 4, lc = lane & 15;
    int wr = w & 1, wc = w >> 1;              // wave: 32 m x 64 d quadrant

    // main: sA [64][64] u16 flat (8KB) | sB [128][64] u16 flat (16KB)
    // epi : sY [64][136] (17.4KB)      | sW/sT [128][136] (34.8KB)
    __shared__ unsigned short lds[26112];     // 52,224 B
    unsigned short* sA = lds;
    unsigned short* sB = lds + 4096;
    unsigned short* sY = lds;                 // 64*136 = 8704
    unsigned short* sW = lds + 8704;          // 128*136 = 17408

    const unsigned short* Sg = S + ((size_t)b << 20);
    const unsigned short* Pb = Pt + (size_t)b * DF * M_;

    floatx4 acc[2][4];
    for (int i = 0; i < 2; ++i)
        for (int j = 0; j < 4; ++j) acc[i][j] = (floatx4){0.f, 0.f, 0.f, 0.f};

    for (int nc = 0; nc < 16; ++nc) {         // BK = 64
        __syncthreads();
        // stage sA: 64 rows x 64 n = 8KB -> 2 rounds of 256 lanes x 16B
        for (int r = 0; r < 2; ++r) {
            int te = r * 256 + w * 64 + lane;
            const void* gp = Sg + (size_t)(m0 + (te >> 3)) * M_ + nc * 64 + (te & 7) * 8;
            load_lds16(gp, (char*)sA + (r * 256 + w * 64) * 16);
        }
        // stage sB: 128 rows x 64 n = 16KB -> 4 rounds
        for (int r = 0; r < 4; ++r) {
            int te = r * 256 + w * 64 + lane;
            const void* gp = Pb + (size_t)(te >> 3) * M_ + nc * 64 + (te & 7) * 8;
            load_lds16(gp, (char*)sB + (r * 256 + w * 64) * 16);
        }
        __syncthreads();
        for (int ks = 0; ks < 2; ++ks) {
            short8 afr[2], bfr[4];
            for (int i = 0; i < 2; ++i)
                afr[i] = *(const short8*)(&sA[(wr * 32 + i * 16 + lc) * 64 + ks * 32 + quad * 8]);
            for (int j = 0; j < 4; ++j)
                bfr[j] = *(const short8*)(&sB[(wc * 64 + j * 16 + lc) * 64 + ks * 32 + quad * 8]);
            for (int i = 0; i < 2; ++i)
                for (int j = 0; j < 4; ++j)
                    acc[i][j] = __builtin_amdgcn_mfma_f32_16x16x32_bf16(afr[i], bfr[j], acc[i][j], 0, 0, 0);
        }
    }

    // ---- epilogue
    float dv[2][4];
    for (int i = 0; i < 2; ++i)
        for (int r = 0; r < 4; ++r)
            dv[i][r] = dinv[b * M_ + m0 + wr * 32 + i * 16 + quad * 4 + r];
    __syncthreads();                          // main-loop LDS reads done
    for (int i = 0; i < 2; ++i)
        for (int j = 0; j < 4; ++j) {
            int mrow = wr * 32 + i * 16 + quad * 4;
            int col = wc * 64 + j * 16 + lc;
            for (int r = 0; r < 4; ++r)
                sY[(mrow + r) * 136 + col] = f2bf(acc[i][j][r] * dv[i][r]);
        }
    // W: 128 x 128 u16 = 2048 short8 chunks -> 8 rounds of 256
    for (int it = 0; it < 8; ++it) {
        int c = t + 256 * it;
        int row = c >> 4, off = (c & 15) * 8;
        *(short8*)(&sW[row * 136 + off]) = *(const short8*)(Wbf + row * DF + off);
    }
    __syncthreads();
    floatx4 accH[2][4];
    for (int i = 0; i < 2; ++i)
        for (int j = 0; j < 4; ++j) accH[i][j] = (floatx4){0.f, 0.f, 0.f, 0.f};
    for (int ks = 0; ks < 4; ++ks) {
        short8 afr[2], bfr[4];
        for (int i = 0; i < 2; ++i)
            afr[i] = *(const short8*)(&sY[(wr * 32 + i * 16 + lc) * 136 + ks * 32 + quad * 8]);
        for (int j = 0; j < 4; ++j)
            bfr[j] = *(const short8*)(&sW[(wc * 64 + j * 16 + lc) * 136 + ks * 32 + quad * 8]);
        for (int i = 0; i < 2; ++i)
            for (int j = 0; j < 4; ++j)
                accH[i][j] = __builtin_amdgcn_mfma_f32_16x16x32_bf16(afr[i], bfr[j], accH[i][j], 0, 0, 0);
    }
    if (MODE == 2) {
        float* Ob = OutF + ((size_t)b * M_ + m0) * DF;
        for (int i = 0; i < 2; ++i)
            for (int j = 0; j < 4; ++j) {
                int mrow = wr * 32 + i * 16 + quad * 4;
                int col = wc * 64 + j * 16 + lc;
                for (int r = 0; r < 4; ++r)
                    Ob[(size_t)(mrow + r) * DF + col] = fmaxf(accH[i][j][r], 0.f);
            }
    } else {
        __syncthreads();                      // sW reads done; reuse as sT [128 o][72]
        unsigned short* sT = sW;
        for (int i = 0; i < 2; ++i)
            for (int j = 0; j < 4; ++j) {
                int mrow = wr * 32 + i * 16 + quad * 4;
                int col = wc * 64 + j * 16 + lc;
                for (int r = 0; r < 4; ++r)
                    sT[col * 72 + mrow + r] = f2bf(fmaxf(accH[i][j][r], 0.f) * dv[i][r]);
            }
        __syncthreads();
        for (int it = 0; it < 4; ++it) {
            int c = t + 256 * it;             // 1024 = 128 o-rows x 8
            int o = c >> 3, off = (c & 7) * 8;
            *(short8*)(OutT + (size_t)(b * DF + o) * M_ + m0 + off) =
                *(const short8*)(&sT[o * 72 + off]);
        }
    }
}

// ================================================================ fallback path (round-1, passed)
__global__ __launch_bounds__(256) void degree_kernel(
    const unsigned short* __restrict__ Ebf, float* __restrict__ dinv) {
    int mt = blockIdx.x, b = blockIdx.y;
    int t = threadIdx.x;
    int w = t >> 6, lane = t & 63, quad = lane >> 4, lc = lane & 15;
    __shared__ unsigned short sEn[128][72];
    const unsigned short* Eb = Ebf + (size_t)b * M_ * ED;
    short8 afr[2][2];
    for (int i = 0; i < 2; ++i) {
        int row = mt * 128 + w * 32 + i * 16 + lc;
        for (int ks = 0; ks < 2; ++ks)
            afr[i][ks] = *(const short8*)(Eb + (size_t)row * ED + ks * 32 + quad * 8);
    }
    floatx4 rsum[2];
    rsum[0] = (floatx4){0.f,0.f,0.f,0.f};
    rsum[1] = (floatx4){0.f,0.f,0.f,0.f};
    for (int nc = 0; nc < 8; ++nc) {
        __syncthreads();
        for (int it = 0; it < 4; ++it) {
            int c = t + 256 * it;
            int row = c >> 3, off = (c & 7) * 8;
            *(short8*)(&sEn[row][off]) =
                *(const short8*)(Eb + (size_t)(nc * 128 + row) * ED + off);
        }
        __syncthreads();
        for (int nt = 0; nt < 8; ++nt) {
            short8 b0 = *(const short8*)(&sEn[nt * 16 + lc][quad * 8]);
            short8 b1 = *(const short8*)(&sEn[nt * 16 + lc][32 + quad * 8]);
            for (int i = 0; i < 2; ++i) {
                floatx4 s = (floatx4){0.f,0.f,0.f,0.f};
                s = __builtin_amdgcn_mfma_f32_16x16x32_bf16(afr[i][0], b0, s, 0, 0, 0);
                s = __builtin_amdgcn_mfma_f32_16x16x32_bf16(afr[i][1], b1, s, 0, 0, 0);
                for (int r = 0; r < 4; ++r) rsum[i][r] += fmaxf(s[r], 0.f);
            }
        }
    }
    for (int i = 0; i < 2; ++i)
        for (int r = 0; r < 4; ++r) {
            float v = rsum[i][r];
            v += __shfl_xor(v, 1, 16);
            v += __shfl_xor(v, 2, 16);
            v += __shfl_xor(v, 4, 16);
            v += __shfl_xor(v, 8, 16);
            if (lc == 0) {
                int row = mt * 128 + w * 32 + i * 16 + quad * 4 + r;
                dinv[b * M_ + row] = rsqrtf(1.0f + v);
            }
        }
}

__global__ __launch_bounds__(256) void tscale128_kernel(
    const float* __restrict__ X, const float* __restrict__ dinv,
    unsigned short* __restrict__ Xt) {
    int mt = blockIdx.x, b = blockIdx.y;
    int t = threadIdx.x;
    __shared__ unsigned short sT[128][136];
    int nloc = t >> 5;
    int d4 = (t & 31) * 4;
    for (int pass = 0; pass < 16; ++pass) {
        int n = pass * 8 + nloc;
        int grow = b * M_ + mt * 128 + n;
        float sc = dinv[grow];
        float4 v = *(const float4*)(X + (size_t)grow * DF + d4);
        sT[d4 + 0][n] = f2bf(v.x * sc);
        sT[d4 + 1][n] = f2bf(v.y * sc);
        sT[d4 + 2][n] = f2bf(v.z * sc);
        sT[d4 + 3][n] = f2bf(v.w * sc);
    }
    __syncthreads();
    for (int it = 0; it < 8; ++it) {
        int c = t + 256 * it;
        int d = c >> 4, off = (c & 15) * 8;
        *(short8*)(Xt + (size_t)(b * DF + d) * M_ + mt * 128 + off) =
            *(const short8*)(&sT[d][off]);
    }
}

template <int MODE>
__global__ __launch_bounds__(256) void gcn_kernel(
    const unsigned short* __restrict__ Ebf,
    const unsigned short* __restrict__ Pt,
    const unsigned short* __restrict__ Wbf,
    const float* __restrict__ dinv,
    unsigned short* __restrict__ OutT,
    float* __restrict__ OutF) {
    int mt = blockIdx.x, b = blockIdx.y;
    int t = threadIdx.x;
    int w = t >> 6, lane = t & 63, quad = lane >> 4, lc = lane & 15;
    int wr = w & 1, wc = w >> 1;
    __shared__ unsigned short sEn[128][72];
    __shared__ unsigned short sS[128][136];
    __shared__ unsigned short sPW[128][136];
    const unsigned short* Eb = Ebf + (size_t)b * M_ * ED;
    short8 ae[4][2];
    for (int i = 0; i < 4; ++i) {
        int row = mt * 128 + wr * 64 + i * 16 + lc;
        for (int ks = 0; ks < 2; ++ks)
            ae[i][ks] = *(const short8*)(Eb + (size_t)row * ED + ks * 32 + quad * 8);
    }
    floatx4 accZ[4][4];
    for (int i = 0; i < 4; ++i)
        for (int j = 0; j < 4; ++j) accZ[i][j] = (floatx4){0.f,0.f,0.f,0.f};
    for (int nc = 0; nc < 8; ++nc) {
        __syncthreads();
        for (int it = 0; it < 4; ++it) {
            int c = t + 256 * it;
            int row = c >> 3, off = (c & 7) * 8;
            *(short8*)(&sEn[row][off]) =
                *(const short8*)(Eb + (size_t)(nc * 128 + row) * ED + off);
        }
        for (int it = 0; it < 8; ++it) {
            int c = t + 256 * it;
            int drow = c >> 4, off = (c & 15) * 8;
            *(short8*)(&sPW[drow][off]) =
                *(const short8*)(Pt + (size_t)(b * DF + drow) * M_ + nc * 128 + off);
        }
        __syncthreads();
        for (int jt = 0; jt < 4; ++jt) {
            int ncol = wc * 64 + jt * 16;
            short8 b0 = *(const short8*)(&sEn[ncol + lc][quad * 8]);
            short8 b1 = *(const short8*)(&sEn[ncol + lc][32 + quad * 8]);
            for (int i = 0; i < 4; ++i) {
                floatx4 s = (floatx4){0.f,0.f,0.f,0.f};
                s = __builtin_amdgcn_mfma_f32_16x16x32_bf16(ae[i][0], b0, s, 0, 0, 0);
                s = __builtin_amdgcn_mfma_f32_16x16x32_bf16(ae[i][1], b1, s, 0, 0, 0);
                int mrow = wr * 64 + i * 16 + quad * 4;
                for (int r = 0; r < 4; ++r) {
                    float v = fmaxf(s[r], 0.f);
                    if (mt == nc && (mrow + r) == (ncol + lc)) v += 1.0f;
                    sS[mrow + r][ncol + lc] = f2bf(v);
                }
            }
        }
        __syncthreads();
        for (int ks = 0; ks < 4; ++ks) {
            short8 afr[4];
            for (int i = 0; i < 4; ++i)
                afr[i] = *(const short8*)(&sS[wr * 64 + i * 16 + lc][ks * 32 + quad * 8]);
            for (int j = 0; j < 4; ++j) {
                short8 bfr = *(const short8*)(&sPW[wc * 64 + j * 16 + lc][ks * 32 + quad * 8]);
                for (int i = 0; i < 4; ++i)
                    accZ[i][j] = __builtin_amdgcn_mfma_f32_16x16x32_bf16(afr[i], bfr, accZ[i][j], 0, 0, 0);
            }
        }
    }
    float dv[4][4];
    for (int i = 0; i < 4; ++i)
        for (int r = 0; r < 4; ++r)
            dv[i][r] = dinv[b * M_ + mt * 128 + wr * 64 + i * 16 + quad * 4 + r];
    __syncthreads();
    for (int i = 0; i < 4; ++i)
        for (int j = 0; j < 4; ++j) {
            int mrow = wr * 64 + i * 16 + quad * 4;
            int col = wc * 64 + j * 16 + lc;
            for (int r = 0; r < 4; ++r)
                sS[mrow + r][col] = f2bf(accZ[i][j][r] * dv[i][r]);
        }
    for (int it = 0; it < 8; ++it) {
        int c = t + 256 * it;
        int row = c >> 4, off = (c & 15) * 8;
        *(short8*)(&sPW[row][off]) = *(const short8*)(Wbf + row * DF + off);
    }
    __syncthreads();
    floatx4 accH[4][4];
    for (int i = 0; i < 4; ++i)
        for (int j = 0; j < 4; ++j) accH[i][j] = (floatx4){0.f,0.f,0.f,0.f};
    for (int ks = 0; ks < 4; ++ks) {
        short8 afr[4], bfr[4];
        for (int i = 0; i < 4; ++i)
            afr[i] = *(const short8*)(&sS[wr * 64 + i * 16 + lc][ks * 32 + quad * 8]);
        for (int j = 0; j < 4; ++j)
            bfr[j] = *(const short8*)(&sPW[wc * 64 + j * 16 + lc][ks * 32 + quad * 8]);
        for (int i = 0; i < 4; ++i)
            for (int j = 0; j < 4; ++j)
                accH[i][j] = __builtin_amdgcn_mfma_f32_16x16x32_bf16(afr[i], bfr[j], accH[i][j], 0, 0, 0);
    }
    if (MODE == 2) {
        float* Ob = OutF + ((size_t)b * M_ + mt * 128) * DF;
        for (int i = 0; i < 4; ++i)
            for (int j = 0; j < 4; ++j) {
                int mrow = wr * 64 + i * 16 + quad * 4;
                int col = wc * 64 + j * 16 + lc;
                for (int r = 0; r < 4; ++r)
                    Ob[(size_t)(mrow + r) * DF + col] = fmaxf(accH[i][j][r], 0.f);
            }
    } else {
        __syncthreads();
        for (int i = 0; i < 4; ++i)
            for (int j = 0; j < 4; ++j) {
                int mrow = wr * 64 + i * 16 + quad * 4;
                int col = wc * 64 + j * 16 + lc;
                for (int r = 0; r < 4; ++r)
                    sS[col][mrow + r] = f2bf(fmaxf(accH[i][j][r], 0.f) * dv[i][r]);
            }
        __syncthreads();
        unsigned short* Ob = OutT + (size_t)b * DF * M_ + mt * 128;
        for (int it = 0; it < 8; ++it) {
            int c = t + 256 * it;
            int orow = c >> 4, off = (c & 15) * 8;
            *(short8*)(Ob + (size_t)orow * M_ + off) = *(const short8*)(&sS[orow][off]);
        }
    }
}

// ---------------------------------------------------------------- launch
extern "C" void kernel_launch(void* const* d_in, const int* in_sizes, int n_in,
                              void* d_out, int out_size, void* d_ws, size_t ws_size,
                              hipStream_t stream) {
    (void)in_sizes; (void)n_in; (void)out_size;
    const float* X  = (const float*)d_in[0];
    const float* E  = (const float*)d_in[1];
    const float* W1 = (const float*)d_in[2];
    const float* W2 = (const float*)d_in[3];
    float* out = (float*)d_out;

    char* ws = (char*)d_ws;
    unsigned short* Ebf  = (unsigned short*)(ws);
    unsigned short* W1bf = (unsigned short*)(ws + 4194304);
    unsigned short* W2bf = (unsigned short*)(ws + 4227072);
    float*          dinv = (float*)(ws + 4259840);
    unsigned short* Xt   = (unsigned short*)(ws + 4390912);
    unsigned short* Ht   = (unsigned short*)(ws + 12779520);
    unsigned short* Smat = (unsigned short*)(ws + 21168128);
    const size_t NEED = 21168128ull + 67108864ull;   // 88,276,992 B

    cast_kernel<<<2080, 256, 0, stream>>>(E, W1, W2, Ebf, W1bf, W2bf);
    if (ws_size >= NEED) {
        build_s_kernel<<<dim3(16, 32), 256, 0, stream>>>(Ebf, Smat, dinv);
        tscale_kernel<<<dim3(16, 32), 256, 0, stream>>>(X, dinv, Xt);
        gemm_kernel<1><<<dim3(16, 32), 256, 0, stream>>>(Smat, Xt, W1bf, dinv, Ht, nullptr);
        gemm_kernel<2><<<dim3(16, 32), 256, 0, stream>>>(Smat, Ht, W2bf, dinv, nullptr, out);
    } else {
        degree_kernel<<<dim3(8, 32), 256, 0, stream>>>(Ebf, dinv);
        tscale128_kernel<<<dim3(8, 32), 256, 0, stream>>>(X, dinv, Xt);
        gcn_kernel<1><<<dim3(8, 32), 256, 0, stream>>>(Ebf, Xt, W1bf, dinv, Ht, nullptr);
        gcn_kernel<2><<<dim3(8, 32), 256, 0, stream>>>(Ebf, Ht, W2bf, dinv, nullptr, out);
    }
}